// Round 14
// baseline (955.941 us; speedup 1.0000x reference)
//
#include <hip/hip_runtime.h>

#define EPS_BN 1e-5f

typedef unsigned int u32;
typedef short short8 __attribute__((ext_vector_type(8)));
typedef float f32x16 __attribute__((ext_vector_type(16)));
typedef _Float16 h4 __attribute__((ext_vector_type(4)));
typedef _Float16 h8f __attribute__((ext_vector_type(8)));

constexpr int N_IN_C  = 100000;
constexpr int N_OUT_C = 400000;
constexpr int KTAPS   = 27;
constexpr int M_UP_C  = 100000;
constexpr int M_C_C   = 120000;

constexpr int WIN     = 256;                    // input window rows
constexpr int SH      = 8;                      // log2(WIN)
constexpr int NWIN    = (N_OUT_C + WIN - 1) / WIN;   // 1563
constexpr int NWIN_U  = (N_IN_C  + WIN - 1) / WIN;   // 391
constexpr int NBA     = NWIN * KTAPS;           // 42201 buckets per stage
constexpr int NBT     = 3 * NBA;                // 126603
constexpr int SCHUNK  = 2048;
constexpr int FCH     = 8192;                   // pairs per fill/hist chunk
constexpr int NCHK    = 15;                     // max chunks per (tap,stage)
constexpr int MAXW    = 1600;                   // >= NWIN
constexpr int WSLOTS  = 7;                      // 7*256 >= NWIN
constexpr int NTILES  = N_OUT_C / 128;          // 3125
constexpr int HSZ     = 3 * KTAPS * NCHK * NWIN;
constexpr int ENTT    = 27 * (M_UP_C + 2 * M_C_C) + NBT * 31 + 64;

__device__ inline unsigned short f2bf(float f) {
    u32 u = __builtin_bit_cast(u32, f);
    return (unsigned short)((u + 0x7FFFu + ((u >> 16) & 1u)) >> 16);
}

// ---------------------------------------------------------------------------
// f32 -> bf16 dense convert (x_skip).
// ---------------------------------------------------------------------------
__global__ __launch_bounds__(256) void cvt_kernel(
    const float* __restrict__ s, ushort* __restrict__ d, int n4)
{
    const int i = blockIdx.x * 256 + threadIdx.x;
    if (i >= n4) return;
    const float4 v = reinterpret_cast<const float4*>(s)[i];
    ushort4 o;
    o.x = f2bf(v.x); o.y = f2bf(v.y); o.z = f2bf(v.z); o.w = f2bf(v.w);
    reinterpret_cast<ushort4*>(d)[i] = o;
}

// ---------------------------------------------------------------------------
// Pack weights into MFMA B-fragment layout, bf16.
// ---------------------------------------------------------------------------
__global__ __launch_bounds__(256) void wpack_kernel(
    const float* __restrict__ wU, const float* __restrict__ w1,
    const float* __restrict__ w2,
    ushort* __restrict__ fU, ushort* __restrict__ f1, ushort* __restrict__ f2)
{
    const int t = blockIdx.x * 256 + threadIdx.x;
    const float* w; ushort* dst; int CIN, NF, local;
    if      (t <  6912) { w = wU; dst = fU; CIN = 64; NF = 4; local = t; }
    else if (t < 13824) { w = w1; dst = f1; CIN = 64; NF = 4; local = t - 6912; }
    else if (t < 17280) { w = w2; dst = f2; CIN = 32; NF = 2; local = t - 13824; }
    else return;
    const int lane = local & 63;
    const int fi   = (local >> 6) % NF;
    const int tap  = local / (64 * NF);
    const int half = lane >> 5, colc = lane & 31;
    ushort* o = dst + ((size_t)(tap * NF + fi) * 64 + lane) * 8;
#pragma unroll
    for (int j = 0; j < 8; ++j) {
        const int k = 16 * fi + 8 * half + j;
        o[j] = f2bf(w[((size_t)tap * CIN + k) * 32 + colc]);
    }
}

// ---------------------------------------------------------------------------
// Atomic-free histogram: per (chunk,tap,stage) block, LDS hist -> contiguous
// write of h[s][k][chunk][0..nwin).
// ---------------------------------------------------------------------------
__global__ __launch_bounds__(256) void histx_kernel(
    const int* __restrict__ i0, const int* __restrict__ i1,
    const int* __restrict__ i2, u32* __restrict__ h)
{
    const int s = blockIdx.z, k = blockIdx.y, c = blockIdx.x;
    const int M    = (s == 0) ? M_UP_C : M_C_C;
    const int nwin = (s == 0) ? NWIN_U : NWIN;
    const int m0 = c * FCH;
    if (m0 >= M) return;
    const int cnt = min(FCH, M - m0);
    const int* idx = (s == 0) ? i0 : (s == 1) ? i1 : i2;

    __shared__ u32 lh[NWIN];
    for (int w = threadIdx.x; w < nwin; w += 256) lh[w] = 0;
    __syncthreads();
    const int* ink = idx + (size_t)k * M + m0;
    for (int i = threadIdx.x; i < cnt; i += 256)
        atomicAdd(&lh[ink[i] >> SH], 1u);
    __syncthreads();
    u32* hp = h + ((size_t)(s * KTAPS + k) * NCHK + c) * NWIN;
    for (int w = threadIdx.x; w < nwin; w += 256) hp[w] = lh[w];
}

// ---------------------------------------------------------------------------
// Per-bucket totals.
// ---------------------------------------------------------------------------
__global__ __launch_bounds__(256) void totals_kernel(
    const u32* __restrict__ h, u32* __restrict__ cnt)
{
    const int s = blockIdx.z, k = blockIdx.y;
    const int w = blockIdx.x * 256 + threadIdx.x;
    if (w >= NWIN) return;
    const u32* hp = h + (size_t)(s * KTAPS + k) * NCHK * NWIN + w;
    u32 t = 0;
#pragma unroll
    for (int c = 0; c < NCHK; ++c) t += hp[(size_t)c * NWIN];
    cnt[(size_t)s * NBA + w * KTAPS + k] = t;
}

// ---------------------------------------------------------------------------
// Hierarchical exclusive scan over NBT buckets (pad each to 32-multiple).
// ---------------------------------------------------------------------------
__global__ __launch_bounds__(256) void scan_part_kernel(
    const u32* __restrict__ cnt, u32* __restrict__ bsum, int nb)
{
    const int i0 = blockIdx.x * SCHUNK + threadIdx.x * 8;
    u32 s = 0;
#pragma unroll
    for (int j = 0; j < 8; ++j) {
        const int i = i0 + j;
        if (i < nb) s += (cnt[i] + 31u) & ~31u;
    }
    __shared__ u32 ls[256];
    ls[threadIdx.x] = s;
    __syncthreads();
    for (int off = 128; off > 0; off >>= 1) {
        if (threadIdx.x < off) ls[threadIdx.x] += ls[threadIdx.x + off];
        __syncthreads();
    }
    if (threadIdx.x == 0) bsum[blockIdx.x] = ls[0];
}

__global__ __launch_bounds__(1024) void scan_bsum_kernel(
    u32* __restrict__ bsum, int nblk)
{
    __shared__ u32 tmp[1024];
    const int t = threadIdx.x;
    const u32 v = (t < nblk) ? bsum[t] : 0u;
    tmp[t] = v;
    __syncthreads();
    for (int off = 1; off < 1024; off <<= 1) {
        const u32 u = (t >= off) ? tmp[t - off] : 0u;
        __syncthreads();
        tmp[t] += u;
        __syncthreads();
    }
    if (t < nblk) bsum[t] = tmp[t] - v;
}

__global__ __launch_bounds__(256) void scan_emit_kernel(
    const u32* __restrict__ cnt, const u32* __restrict__ bsum,
    u32* __restrict__ starts, int nb)
{
    const int t  = threadIdx.x;
    const int i0 = blockIdx.x * SCHUNK + t * 8;
    u32 vals[8];
    u32 s = 0;
#pragma unroll
    for (int j = 0; j < 8; ++j) {
        const int i = i0 + j;
        u32 c = (i < nb) ? cnt[i] : 0u;
        c = (c + 31u) & ~31u;
        vals[j] = c;
        s += c;
    }
    __shared__ u32 ls[256];
    ls[t] = s;
    __syncthreads();
    for (int off = 1; off < 256; off <<= 1) {
        const u32 u = (t >= off) ? ls[t - off] : 0u;
        __syncthreads();
        ls[t] += u;
        __syncthreads();
    }
    u32 run = bsum[blockIdx.x] + ls[t] - s;
#pragma unroll
    for (int j = 0; j < 8; ++j) {
        const int i = i0 + j;
        if (i < nb) starts[i] = run;
        run += vals[j];
    }
    if (blockIdx.x == gridDim.x - 1 && t == 255) starts[nb] = run;
}

// ---------------------------------------------------------------------------
// Per-(bucket,chunk) bases.
// ---------------------------------------------------------------------------
__global__ __launch_bounds__(256) void pbase_kernel(
    const u32* __restrict__ h, const u32* __restrict__ starts,
    u32* __restrict__ pb)
{
    const int s = blockIdx.z, k = blockIdx.y;
    const int w = blockIdx.x * 256 + threadIdx.x;
    if (w >= NWIN) return;
    u32 run = starts[(size_t)s * NBA + w * KTAPS + k];
    const size_t base = (size_t)(s * KTAPS + k) * NCHK * NWIN + w;
#pragma unroll
    for (int c = 0; c < NCHK; ++c) {
        pb[base + (size_t)c * NWIN] = run;
        run += h[base + (size_t)c * NWIN];
    }
}

// ---------------------------------------------------------------------------
// Atomic-free binned fill (unchanged from R13).
// ---------------------------------------------------------------------------
__global__ __launch_bounds__(256) void fill_kernel(
    const int* __restrict__ in0, const int* __restrict__ out0,
    const int* __restrict__ in1, const int* __restrict__ out1,
    const int* __restrict__ in2, const int* __restrict__ out2,
    const u32* __restrict__ pb, u32* __restrict__ entryA)
{
    __shared__ u32 hist[MAXW];
    __shared__ u32 lofs[MAXW];
    __shared__ u32 gbase[MAXW];
    __shared__ u32 lent[FCH];
    __shared__ u32 psum[256];

    const int s = blockIdx.z;
    const int* in_idx  = (s == 0) ? in0  : (s == 1) ? in1  : in2;
    const int* out_idx = (s == 0) ? out0 : (s == 1) ? out1 : out2;
    const int  M       = (s == 0) ? M_UP_C : M_C_C;
    const int  nwin    = (s == 0) ? NWIN_U : NWIN;

    const int k   = blockIdx.y;
    const int m0  = blockIdx.x * FCH;
    if (m0 >= M) return;
    const int cnt = min(FCH, M - m0);
    const int t   = threadIdx.x;

    const u32* pbk = pb + ((size_t)(s * KTAPS + k) * NCHK + blockIdx.x) * NWIN;

    for (int w = t; w < nwin; w += 256) {
        hist[w]  = 0;
        gbase[w] = pbk[w];
    }
    __syncthreads();

    const int* ink  = in_idx  + (size_t)k * M + m0;
    const int* outk = out_idx + (size_t)k * M + m0;

    for (int i = t; i < cnt; i += 256)
        atomicAdd(&hist[ink[i] >> SH], 1u);
    __syncthreads();

    u32 loc[WSLOTS];
    u32 ssum = 0;
#pragma unroll
    for (int j = 0; j < WSLOTS; ++j) {
        const int w = t * WSLOTS + j;
        const u32 c = (w < nwin) ? hist[w] : 0u;
        loc[j] = ssum;
        ssum += c;
    }
    psum[t] = ssum;
    __syncthreads();
    for (int off = 1; off < 256; off <<= 1) {
        const u32 v = (t >= off) ? psum[t - off] : 0u;
        __syncthreads();
        psum[t] += v;
        __syncthreads();
    }
    const u32 tbase = psum[t] - ssum;
#pragma unroll
    for (int j = 0; j < WSLOTS; ++j) {
        const int w = t * WSLOTS + j;
        if (w < nwin) lofs[w] = tbase + loc[j];
    }
    __syncthreads();

    for (int i = t; i < cnt; i += 256) {
        const int in = ink[i];
        const int o  = outk[i];
        const int w  = in >> SH;
        const u32 pp = atomicAdd(&lofs[w], 1u);
        lent[pp] = ((u32)(in & (WIN - 1)) << 19) | (u32)o;
    }
    __syncthreads();

    for (int w = t; w < nwin; w += 256) {
        const u32 c = hist[w];
        if (!c) continue;
        const u32 lo = lofs[w] - c;
        const u32 gb = gbase[w];
        for (u32 j = 0; j < c; ++j)
            entryA[gb + j] = lent[lo + j];
    }
}

// ---------------------------------------------------------------------------
// Conv with fused BN+ReLU staging. LDS = win only (32KB NF=4 -> 5 blk/CU,
// 16KB NF=2 -> 8 blk/CU). Per-thread BN scale/bias in REGISTERS: staging
// stride 256 === 0 mod NCH so ch = tid%NCH is loop-invariant.
// MODE 0: src = x fp32 64ch raw.  MODE 1: srcA = prev fp16 acc (BN),
// srcB = x_skip bf16 raw.  MODE 2: src = prev fp16 acc (BN).
// ---------------------------------------------------------------------------
template <int NF, int MODE>
__global__ __launch_bounds__(256) void conv_kernel(
    const void* __restrict__ srcAv, const void* __restrict__ srcBv,
    const ushort* __restrict__ wfrag,
    const u32* __restrict__ entryA, const u32* __restrict__ starts,
    const float* __restrict__ st, const float* __restrict__ g,
    const float* __restrict__ bt, float invn,
    _Float16* __restrict__ accH, int n_src)
{
    constexpr int NCH = NF * 2;
    constexpr int RPL = 8 / NCH;
    __shared__ ushort win[WIN * NF * 16];   // exactly 32KB (NF=4) / 16KB (NF=2)

    const int w0   = blockIdx.x * WIN;
    const int tid  = threadIdx.x;
    const int lane = tid & 63;
    const int wid  = tid >> 6;
    const int col  = lane & 31;
    const int half = lane >> 5;
    const int ch0  = tid % NCH;             // loop-invariant staging channel

    // per-thread BN params for the 8 channels this thread stages
    float sc8[8], bi8[8];
    const bool needbn = (MODE == 2) || (MODE == 1 && ch0 < 4);
    if (MODE != 0 && needbn) {
#pragma unroll
        for (int j = 0; j < 8; ++j) {
            const int c = ch0 * 8 + j;
            const float m   = st[c] * invn;
            const float var = fmaxf(st[32 + c] * invn - m * m, 0.f);
            const float s_  = rsqrtf(var + EPS_BN) * g[c];
            sc8[j] = s_;
            bi8[j] = fmaf(-m, s_, bt[c]);
        }
    }

    for (int i = tid; i < WIN * NCH; i += 256) {
        const int r  = i / NCH;             // ch == ch0 always
        const int row = w0 + r;
        short8 v = {0, 0, 0, 0, 0, 0, 0, 0};
        if (row < n_src) {
            if (MODE == 0) {
                const float* sp = (const float*)srcAv + (size_t)row * 64 + ch0 * 8;
#pragma unroll
                for (int j = 0; j < 8; ++j) v[j] = (short)f2bf(sp[j]);
            } else if (MODE == 1) {
                if (ch0 < 4) {
                    const h8f hv = *reinterpret_cast<const h8f*>(
                        (const _Float16*)srcAv + (size_t)row * 32 + ch0 * 8);
#pragma unroll
                    for (int j = 0; j < 8; ++j) {
                        const float y = fmaf(sc8[j], (float)hv[j], bi8[j]);
                        v[j] = (short)f2bf(y > 0.f ? y : 0.f);
                    }
                } else {
                    v = *reinterpret_cast<const short8*>(
                        (const ushort*)srcBv + (size_t)row * 32 + (ch0 - 4) * 8);
                }
            } else {
                const h8f hv = *reinterpret_cast<const h8f*>(
                    (const _Float16*)srcAv + (size_t)row * 32 + ch0 * 8);
#pragma unroll
                for (int j = 0; j < 8; ++j) {
                    const float y = fmaf(sc8[j], (float)hv[j], bi8[j]);
                    v[j] = (short)f2bf(y > 0.f ? y : 0.f);
                }
            }
        }
        const int addr = (r / RPL) * 64 + ((((r % RPL) * NCH + ch0) ^ ((r / RPL) & 7)) * 8);
        *reinterpret_cast<short8*>(&win[addr]) = v;
    }
    __syncthreads();

    const short8* wf8 = reinterpret_cast<const short8*>(wfrag);

    for (int tap = blockIdx.y * 4 + wid; tap < KTAPS; tap += 8) {
        short8 bf[NF];
#pragma unroll
        for (int f = 0; f < NF; ++f) bf[f] = wf8[(tap * NF + f) * 64 + lane];

        const int b  = blockIdx.x * KTAPS + tap;
        const int s0 = (int)starts[b];
        const int s1 = (int)starts[b + 1];

        for (int bb = s0; bb < s1; bb += 32) {
            const u32 e  = entryA[bb + col];
            const int r  = (int)(e >> 19) & (WIN - 1);
            const int ro = (int)(e & 0x7FFFFu);

            short8 af[NF];
#pragma unroll
            for (int f = 0; f < NF; ++f) {
                const int ch   = f * 2 + half;
                const int addr = (r / RPL) * 64 +
                                 ((((r % RPL) * NCH + ch) ^ ((r / RPL) & 7)) * 8);
                af[f] = *reinterpret_cast<const short8*>(&win[addr]);
            }

            f32x16 cacc;
#pragma unroll
            for (int rr = 0; rr < 16; ++rr) cacc[rr] = 0.f;
#pragma unroll
            for (int f = 0; f < NF; ++f)
                cacc = __builtin_amdgcn_mfma_f32_32x32x16_bf16(af[f], bf[f], cacc, 0, 0, 0);

            const bool oddl = lane & 1;
#pragma unroll
            for (int rr = 0; rr < 16; rr += 2) {
                const int pr0  = (rr & 3) + 8 * (rr >> 2) + 4 * half;
                const int pr1  = ((rr + 1) & 3) + 8 * ((rr + 1) >> 2) + 4 * half;
                const int row0 = __shfl(ro, pr0);
                const int row1 = __shfl(ro, pr1);
                const float a  = cacc[rr], bb2 = cacc[rr + 1];
                const float a2 = __shfl_xor(a, 1);
                const float b2 = __shfl_xor(bb2, 1);
                const float lo = oddl ? b2  : a;
                const float hi = oddl ? bb2 : a2;
                const int  row = oddl ? row1 : row0;
                if (row != 0x7FFFF) {
                    const u32 pk = __builtin_bit_cast(u32,
                        __builtin_amdgcn_cvt_pkrtz(lo, hi));
                    void* ap = (char*)accH + ((size_t)row << 6) + ((u32)(col >> 1) << 2);
                    asm volatile("global_atomic_pk_add_f16 %0, %1, off"
                                 :: "v"(ap), "v"(pk) : "memory");
                }
            }
        }
    }
}

// ---------------------------------------------------------------------------
// BN stats over fp16 acc (HW fp32 atomics into stats[64]).
// ---------------------------------------------------------------------------
__global__ __launch_bounds__(256) void stats_kernel(
    const _Float16* __restrict__ accH, float* __restrict__ stats)
{
    const int tile = blockIdx.x;
    const int tid  = threadIdx.x;
    const int grp  = tid >> 3;
    const int j    = tid & 7;
    float cs[4] = {0.f, 0.f, 0.f, 0.f};
    float cq[4] = {0.f, 0.f, 0.f, 0.f};
    for (int rr = grp; rr < 128; rr += 32) {
        const h4 v = *reinterpret_cast<const h4*>(
            &accH[(size_t)(tile * 128 + rr) * 32 + j * 4]);
#pragma unroll
        for (int jj = 0; jj < 4; ++jj) {
            const float f = (float)v[jj];
            cs[jj] += f;
            cq[jj] = fmaf(f, f, cq[jj]);
        }
    }
    __shared__ float ls[32][33], lq[32][33];
#pragma unroll
    for (int jj = 0; jj < 4; ++jj) {
        ls[grp][j * 4 + jj] = cs[jj];
        lq[grp][j * 4 + jj] = cq[jj];
    }
    __syncthreads();
    if (tid < 32) {
        float ts = 0.f, tq = 0.f;
#pragma unroll
        for (int gg = 0; gg < 32; ++gg) { ts += ls[gg][tid]; tq += lq[gg][tid]; }
        unsafeAtomicAdd(&stats[tid], ts);
        unsafeAtomicAdd(&stats[32 + tid], tq);
    }
}

// ---------------------------------------------------------------------------
// Final BN+ReLU -> f32 output.
// ---------------------------------------------------------------------------
__global__ __launch_bounds__(256) void bnout_kernel(
    const _Float16* __restrict__ hsrc,
    const float* __restrict__ stats,
    const float* __restrict__ g,
    const float* __restrict__ bt,
    float* __restrict__ dst, int n)
{
    const int i = blockIdx.x * 256 + threadIdx.x;
    if (i >= n * 8) return;
    const h4 v = *reinterpret_cast<const h4*>(&hsrc[(size_t)i * 4]);
    const int c0 = (i & 7) * 4;
    const float invn = 1.f / (float)n;
    float o[4];
#pragma unroll
    for (int j = 0; j < 4; ++j) {
        const int c   = c0 + j;
        const float m   = stats[c] * invn;
        const float var = fmaxf(stats[32 + c] * invn - m * m, 0.f);
        const float s_  = rsqrtf(var + EPS_BN) * g[c];
        float y = ((float)v[j] - m) * s_ + bt[c];
        o[j] = y > 0.f ? y : 0.f;
    }
    float4 w = {o[0], o[1], o[2], o[3]};
    reinterpret_cast<float4*>(dst)[i] = w;
}

// ---------------------------------------------------------------------------
extern "C" void kernel_launch(void* const* d_in, const int* in_sizes, int n_in,
                              void* d_out, int out_size, void* d_ws, size_t ws_size,
                              hipStream_t stream)
{
    const float* x      = (const float*)d_in[0];
    const float* x_skip = (const float*)d_in[1];
    const float* w_up   = (const float*)d_in[2];
    // d_in[3] = b_up cancels exactly through train-mode BN -> unused.
    const float* g_up   = (const float*)d_in[4];
    const float* bt_up  = (const float*)d_in[5];
    const float* w1     = (const float*)d_in[6];
    const float* g1     = (const float*)d_in[7];
    const float* bt1    = (const float*)d_in[8];
    const float* w2     = (const float*)d_in[9];
    const float* g2     = (const float*)d_in[10];
    const float* bt2    = (const float*)d_in[11];
    const int* up_in    = (const int*)d_in[12];
    const int* up_out   = (const int*)d_in[13];
    const int* c1_in    = (const int*)d_in[14];
    const int* c1_out   = (const int*)d_in[15];
    const int* c2_in    = (const int*)d_in[16];
    const int* c2_out   = (const int*)d_in[17];

    // ---- workspace carve ----
    char* p = (char*)d_ws;
    auto alloc = [&](size_t bytes) { char* r = p; p += (bytes + 255) & ~(size_t)255; return r; };
    _Float16* accA   = (_Float16*) alloc((size_t)N_OUT_C * 32 * 2);   // 25.6 MB
    _Float16* accB   = (_Float16*) alloc((size_t)N_OUT_C * 32 * 2);   // 25.6 MB
    ushort*   skip16 = (ushort*)   alloc((size_t)N_OUT_C * 32 * 2);   // 25.6 MB
    ushort*   wfU    = (ushort*)   alloc(27 * 4 * 64 * 8 * 2);
    ushort*   wf1    = (ushort*)   alloc(27 * 4 * 64 * 8 * 2);
    ushort*   wf2    = (ushort*)   alloc(27 * 2 * 64 * 8 * 2);
    float*    stats  = (float*)    alloc(192 * 4);
    u32*      bsum   = (u32*)      alloc(1024 * 4);
    u32*      htab   = (u32*)      alloc((size_t)HSZ * 4);            // 7.6 MB
    u32*      pbase  = (u32*)      alloc((size_t)HSZ * 4);            // 7.6 MB
    u32*      cnt    = (u32*)      alloc((size_t)NBT * 4);
    u32*      starts = (u32*)      alloc((size_t)(NBT + 1) * 4);
    u32*      entryA = (u32*)      alloc((size_t)ENTT * 4);           // 52.4 MB

    float* out = (float*)d_out;
    const dim3 blk(256);
    const float invn = 1.f / (float)N_OUT_C;
    const int nblkS = (NBT + SCHUNK - 1) / SCHUNK;              // 62
    const dim3 gChunk(NCHK, KTAPS, 3);                          // 15x27x3
    const dim3 gWinKS((NWIN + 255) / 256, KTAPS, 3);            // 7x27x3
    const int bn_blocks = (N_OUT_C * 8 + 255) / 256;
    const size_t accBytes = (size_t)N_OUT_C * 32 * 2;

    // ---- prep: weights + skip bf16 + fully atomic-free sort ----
    wpack_kernel<<<(17280 + 255) / 256, blk, 0, stream>>>(w_up, w1, w2, wfU, wf1, wf2);
    cvt_kernel<<<(N_OUT_C * 8 + 255) / 256, blk, 0, stream>>>(x_skip, skip16, N_OUT_C * 8);
    hipMemsetAsync(stats, 0, 192 * sizeof(float), stream);
    hipMemsetAsync(htab, 0, (size_t)HSZ * 4, stream);
    hipMemsetAsync(entryA, 0xFF, (size_t)ENTT * 4, stream);
    histx_kernel<<<gChunk, blk, 0, stream>>>(up_in, c1_in, c2_in, htab);
    totals_kernel<<<gWinKS, blk, 0, stream>>>(htab, cnt);
    scan_part_kernel<<<nblkS, blk, 0, stream>>>(cnt, bsum, NBT);
    scan_bsum_kernel<<<1, 1024, 0, stream>>>(bsum, nblkS);
    scan_emit_kernel<<<nblkS, blk, 0, stream>>>(cnt, bsum, starts, NBT);
    pbase_kernel<<<gWinKS, blk, 0, stream>>>(htab, starts, pbase);
    fill_kernel<<<gChunk, blk, 0, stream>>>(up_in, up_out, c1_in, c1_out,
                                            c2_in, c2_out, pbase, entryA);

    // ---- stage 1: up conv (x fp32 64ch) -> accA ----
    hipMemsetAsync(accA, 0, accBytes, stream);
    conv_kernel<4, 0><<<dim3(NWIN_U, 2), blk, 0, stream>>>(
        x, nullptr, wfU, entryA, starts, stats, g_up, bt_up, invn, accA, N_IN_C);
    stats_kernel<<<NTILES, blk, 0, stream>>>(accA, stats);

    // ---- stage 2: conv1 (bn(accA) | skip16) -> accB ----
    hipMemsetAsync(accB, 0, accBytes, stream);
    conv_kernel<4, 1><<<dim3(NWIN, 2), blk, 0, stream>>>(
        accA, skip16, wf1, entryA, starts + NBA, stats, g_up, bt_up, invn, accB, N_OUT_C);
    stats_kernel<<<NTILES, blk, 0, stream>>>(accB, stats + 64);

    // ---- stage 3: conv2 (bn(accB)) -> accA ----
    hipMemsetAsync(accA, 0, accBytes, stream);
    conv_kernel<2, 2><<<dim3(NWIN, 2), blk, 0, stream>>>(
        accB, nullptr, wf2, entryA, starts + 2 * NBA, stats + 64, g1, bt1, invn, accA, N_OUT_C);
    stats_kernel<<<NTILES, blk, 0, stream>>>(accA, stats + 128);

    // ---- final BN+ReLU -> d_out (f32) ----
    bnout_kernel<<<bn_blocks, blk, 0, stream>>>(accA, stats + 128, g2, bt2, out, N_OUT_C);
}

// Round 15
// 912.759 us; speedup vs baseline: 1.0473x; 1.0473x over previous
//
#include <hip/hip_runtime.h>

#define EPS_BN 1e-5f

typedef unsigned int u32;
typedef short short8 __attribute__((ext_vector_type(8)));
typedef float f32x16 __attribute__((ext_vector_type(16)));
typedef _Float16 h4 __attribute__((ext_vector_type(4)));
typedef _Float16 h8f __attribute__((ext_vector_type(8)));

constexpr int N_IN_C  = 100000;
constexpr int N_OUT_C = 400000;
constexpr int KTAPS   = 27;
constexpr int M_UP_C  = 100000;
constexpr int M_C_C   = 120000;

constexpr int WIN     = 256;                    // input window rows
constexpr int SH      = 8;                      // log2(WIN)
constexpr int NWIN    = (N_OUT_C + WIN - 1) / WIN;   // 1563
constexpr int NWIN_U  = (N_IN_C  + WIN - 1) / WIN;   // 391
constexpr int NBA     = NWIN * KTAPS;           // 42201 buckets per stage
constexpr int NBT     = 3 * NBA;                // 126603
constexpr int SCHUNK  = 2048;
constexpr int FCH     = 8192;                   // pairs per fill/hist chunk
constexpr int NCHK    = 15;                     // max chunks per (tap,stage)
constexpr int MAXW    = 1600;                   // >= NWIN
constexpr int WSLOTS  = 7;                      // 7*256 >= NWIN
constexpr int NTILES  = N_OUT_C / 128;          // 3125
constexpr int HSZ     = 3 * KTAPS * NCHK * NWIN;
constexpr int ENTT    = 27 * (M_UP_C + 2 * M_C_C);   // exact 9.18M entries

__device__ inline unsigned short f2bf(float f) {
    u32 u = __builtin_bit_cast(u32, f);
    return (unsigned short)((u + 0x7FFFu + ((u >> 16) & 1u)) >> 16);
}

// ---------------------------------------------------------------------------
// Pack weights into MFMA B-fragment layout, bf16.
// ---------------------------------------------------------------------------
__global__ __launch_bounds__(256) void wpack_kernel(
    const float* __restrict__ wU, const float* __restrict__ w1,
    const float* __restrict__ w2,
    ushort* __restrict__ fU, ushort* __restrict__ f1, ushort* __restrict__ f2)
{
    const int t = blockIdx.x * 256 + threadIdx.x;
    const float* w; ushort* dst; int CIN, NF, local;
    if      (t <  6912) { w = wU; dst = fU; CIN = 64; NF = 4; local = t; }
    else if (t < 13824) { w = w1; dst = f1; CIN = 64; NF = 4; local = t - 6912; }
    else if (t < 17280) { w = w2; dst = f2; CIN = 32; NF = 2; local = t - 13824; }
    else return;
    const int lane = local & 63;
    const int fi   = (local >> 6) % NF;
    const int tap  = local / (64 * NF);
    const int half = lane >> 5, colc = lane & 31;
    ushort* o = dst + ((size_t)(tap * NF + fi) * 64 + lane) * 8;
#pragma unroll
    for (int j = 0; j < 8; ++j) {
        const int k = 16 * fi + 8 * half + j;
        o[j] = f2bf(w[((size_t)tap * CIN + k) * 32 + colc]);
    }
}

// ---------------------------------------------------------------------------
// Atomic-free histogram: per (chunk,tap,stage) block, LDS hist -> contiguous
// write of h[s][k][chunk][0..nwin).
// ---------------------------------------------------------------------------
__global__ __launch_bounds__(256) void histx_kernel(
    const int* __restrict__ i0, const int* __restrict__ i1,
    const int* __restrict__ i2, u32* __restrict__ h)
{
    const int s = blockIdx.z, k = blockIdx.y, c = blockIdx.x;
    const int M    = (s == 0) ? M_UP_C : M_C_C;
    const int nwin = (s == 0) ? NWIN_U : NWIN;
    const int m0 = c * FCH;
    if (m0 >= M) return;
    const int cnt = min(FCH, M - m0);
    const int* idx = (s == 0) ? i0 : (s == 1) ? i1 : i2;

    __shared__ u32 lh[NWIN];
    for (int w = threadIdx.x; w < nwin; w += 256) lh[w] = 0;
    __syncthreads();
    const int* ink = idx + (size_t)k * M + m0;
    for (int i = threadIdx.x; i < cnt; i += 256)
        atomicAdd(&lh[ink[i] >> SH], 1u);
    __syncthreads();
    u32* hp = h + ((size_t)(s * KTAPS + k) * NCHK + c) * NWIN;
    for (int w = threadIdx.x; w < nwin; w += 256) hp[w] = lh[w];
}

// ---------------------------------------------------------------------------
// Per-bucket totals.
// ---------------------------------------------------------------------------
__global__ __launch_bounds__(256) void totals_kernel(
    const u32* __restrict__ h, u32* __restrict__ cnt)
{
    const int s = blockIdx.z, k = blockIdx.y;
    const int w = blockIdx.x * 256 + threadIdx.x;
    if (w >= NWIN) return;
    const u32* hp = h + (size_t)(s * KTAPS + k) * NCHK * NWIN + w;
    u32 t = 0;
#pragma unroll
    for (int c = 0; c < NCHK; ++c) t += hp[(size_t)c * NWIN];
    cnt[(size_t)s * NBA + w * KTAPS + k] = t;
}

// ---------------------------------------------------------------------------
// Hierarchical exclusive scan over NBT buckets (EXACT, no padding).
// ---------------------------------------------------------------------------
__global__ __launch_bounds__(256) void scan_part_kernel(
    const u32* __restrict__ cnt, u32* __restrict__ bsum, int nb)
{
    const int i0 = blockIdx.x * SCHUNK + threadIdx.x * 8;
    u32 s = 0;
#pragma unroll
    for (int j = 0; j < 8; ++j) {
        const int i = i0 + j;
        if (i < nb) s += cnt[i];
    }
    __shared__ u32 ls[256];
    ls[threadIdx.x] = s;
    __syncthreads();
    for (int off = 128; off > 0; off >>= 1) {
        if (threadIdx.x < off) ls[threadIdx.x] += ls[threadIdx.x + off];
        __syncthreads();
    }
    if (threadIdx.x == 0) bsum[blockIdx.x] = ls[0];
}

__global__ __launch_bounds__(1024) void scan_bsum_kernel(
    u32* __restrict__ bsum, int nblk)
{
    __shared__ u32 tmp[1024];
    const int t = threadIdx.x;
    const u32 v = (t < nblk) ? bsum[t] : 0u;
    tmp[t] = v;
    __syncthreads();
    for (int off = 1; off < 1024; off <<= 1) {
        const u32 u = (t >= off) ? tmp[t - off] : 0u;
        __syncthreads();
        tmp[t] += u;
        __syncthreads();
    }
    if (t < nblk) bsum[t] = tmp[t] - v;
}

__global__ __launch_bounds__(256) void scan_emit_kernel(
    const u32* __restrict__ cnt, const u32* __restrict__ bsum,
    u32* __restrict__ starts, int nb)
{
    const int t  = threadIdx.x;
    const int i0 = blockIdx.x * SCHUNK + t * 8;
    u32 vals[8];
    u32 s = 0;
#pragma unroll
    for (int j = 0; j < 8; ++j) {
        const int i = i0 + j;
        const u32 c = (i < nb) ? cnt[i] : 0u;
        vals[j] = c;
        s += c;
    }
    __shared__ u32 ls[256];
    ls[t] = s;
    __syncthreads();
    for (int off = 1; off < 256; off <<= 1) {
        const u32 u = (t >= off) ? ls[t - off] : 0u;
        __syncthreads();
        ls[t] += u;
        __syncthreads();
    }
    u32 run = bsum[blockIdx.x] + ls[t] - s;
#pragma unroll
    for (int j = 0; j < 8; ++j) {
        const int i = i0 + j;
        if (i < nb) starts[i] = run;
        run += vals[j];
    }
    if (blockIdx.x == gridDim.x - 1 && t == 255) starts[nb] = run;
}

// ---------------------------------------------------------------------------
// Per-(bucket,chunk) bases.
// ---------------------------------------------------------------------------
__global__ __launch_bounds__(256) void pbase_kernel(
    const u32* __restrict__ h, const u32* __restrict__ starts,
    u32* __restrict__ pb)
{
    const int s = blockIdx.z, k = blockIdx.y;
    const int w = blockIdx.x * 256 + threadIdx.x;
    if (w >= NWIN) return;
    u32 run = starts[(size_t)s * NBA + w * KTAPS + k];
    const size_t base = (size_t)(s * KTAPS + k) * NCHK * NWIN + w;
#pragma unroll
    for (int c = 0; c < NCHK; ++c) {
        pb[base + (size_t)c * NWIN] = run;
        run += h[base + (size_t)c * NWIN];
    }
}

// ---------------------------------------------------------------------------
// Atomic-free binned fill (deterministic bases from pbase).
// Entry = (in & (WIN-1)) << 19 | out_row.
// ---------------------------------------------------------------------------
__global__ __launch_bounds__(256) void fill_kernel(
    const int* __restrict__ in0, const int* __restrict__ out0,
    const int* __restrict__ in1, const int* __restrict__ out1,
    const int* __restrict__ in2, const int* __restrict__ out2,
    const u32* __restrict__ pb, u32* __restrict__ entryA)
{
    __shared__ u32 hist[MAXW];
    __shared__ u32 lofs[MAXW];
    __shared__ u32 gbase[MAXW];
    __shared__ u32 lent[FCH];
    __shared__ u32 psum[256];

    const int s = blockIdx.z;
    const int* in_idx  = (s == 0) ? in0  : (s == 1) ? in1  : in2;
    const int* out_idx = (s == 0) ? out0 : (s == 1) ? out1 : out2;
    const int  M       = (s == 0) ? M_UP_C : M_C_C;
    const int  nwin    = (s == 0) ? NWIN_U : NWIN;

    const int k   = blockIdx.y;
    const int m0  = blockIdx.x * FCH;
    if (m0 >= M) return;
    const int cnt = min(FCH, M - m0);
    const int t   = threadIdx.x;

    const u32* pbk = pb + ((size_t)(s * KTAPS + k) * NCHK + blockIdx.x) * NWIN;

    for (int w = t; w < nwin; w += 256) {
        hist[w]  = 0;
        gbase[w] = pbk[w];
    }
    __syncthreads();

    const int* ink  = in_idx  + (size_t)k * M + m0;
    const int* outk = out_idx + (size_t)k * M + m0;

    for (int i = t; i < cnt; i += 256)
        atomicAdd(&hist[ink[i] >> SH], 1u);
    __syncthreads();

    u32 loc[WSLOTS];
    u32 ssum = 0;
#pragma unroll
    for (int j = 0; j < WSLOTS; ++j) {
        const int w = t * WSLOTS + j;
        const u32 c = (w < nwin) ? hist[w] : 0u;
        loc[j] = ssum;
        ssum += c;
    }
    psum[t] = ssum;
    __syncthreads();
    for (int off = 1; off < 256; off <<= 1) {
        const u32 v = (t >= off) ? psum[t - off] : 0u;
        __syncthreads();
        psum[t] += v;
        __syncthreads();
    }
    const u32 tbase = psum[t] - ssum;
#pragma unroll
    for (int j = 0; j < WSLOTS; ++j) {
        const int w = t * WSLOTS + j;
        if (w < nwin) lofs[w] = tbase + loc[j];
    }
    __syncthreads();

    for (int i = t; i < cnt; i += 256) {
        const int in = ink[i];
        const int o  = outk[i];
        const int w  = in >> SH;
        const u32 pp = atomicAdd(&lofs[w], 1u);
        lent[pp] = ((u32)(in & (WIN - 1)) << 19) | (u32)o;
    }
    __syncthreads();

    for (int w = t; w < nwin; w += 256) {
        const u32 c = hist[w];
        if (!c) continue;
        const u32 lo = lofs[w] - c;
        const u32 gb = gbase[w];
        for (u32 j = 0; j < c; ++j)
            entryA[gb + j] = lent[lo + j];
    }
}

// ---------------------------------------------------------------------------
// Conv with fused BN+ReLU staging; tail-masked batches (no sentinel pad).
// MODE 0: src = x fp32 64ch raw.  MODE 1: srcA = prev fp16 acc (BN),
// srcB = x_skip fp32 raw.  MODE 2: src = prev fp16 acc (BN).
// Scatter via packed fp16 HW atomics.
// ---------------------------------------------------------------------------
template <int NF, int MODE>
__global__ __launch_bounds__(256) void conv_kernel(
    const void* __restrict__ srcAv, const void* __restrict__ srcBv,
    const ushort* __restrict__ wfrag,
    const u32* __restrict__ entryA, const u32* __restrict__ starts,
    const float* __restrict__ st, const float* __restrict__ g,
    const float* __restrict__ bt, float invn,
    _Float16* __restrict__ accH, int n_src)
{
    constexpr int NCH = NF * 2;
    constexpr int RPL = 8 / NCH;
    __shared__ ushort win[WIN * NF * 16];   // 32KB (NF=4) / 16KB (NF=2)

    const int w0   = blockIdx.x * WIN;
    const int tid  = threadIdx.x;
    const int lane = tid & 63;
    const int wid  = tid >> 6;
    const int col  = lane & 31;
    const int half = lane >> 5;
    const int ch0  = tid % NCH;             // loop-invariant staging channel

    float sc8[8], bi8[8];
    const bool needbn = (MODE == 2) || (MODE == 1 && ch0 < 4);
    if (MODE != 0 && needbn) {
#pragma unroll
        for (int j = 0; j < 8; ++j) {
            const int c = ch0 * 8 + j;
            const float m   = st[c] * invn;
            const float var = fmaxf(st[32 + c] * invn - m * m, 0.f);
            const float s_  = rsqrtf(var + EPS_BN) * g[c];
            sc8[j] = s_;
            bi8[j] = fmaf(-m, s_, bt[c]);
        }
    }

    for (int i = tid; i < WIN * NCH; i += 256) {
        const int r  = i / NCH;
        const int row = w0 + r;
        short8 v = {0, 0, 0, 0, 0, 0, 0, 0};
        if (row < n_src) {
            if (MODE == 0) {
                const float* sp = (const float*)srcAv + (size_t)row * 64 + ch0 * 8;
#pragma unroll
                for (int j = 0; j < 8; ++j) v[j] = (short)f2bf(sp[j]);
            } else if (MODE == 1) {
                if (ch0 < 4) {
                    const h8f hv = *reinterpret_cast<const h8f*>(
                        (const _Float16*)srcAv + (size_t)row * 32 + ch0 * 8);
#pragma unroll
                    for (int j = 0; j < 8; ++j) {
                        const float y = fmaf(sc8[j], (float)hv[j], bi8[j]);
                        v[j] = (short)f2bf(y > 0.f ? y : 0.f);
                    }
                } else {
                    const float* sp = (const float*)srcBv + (size_t)row * 32 + (ch0 - 4) * 8;
#pragma unroll
                    for (int j = 0; j < 8; ++j) v[j] = (short)f2bf(sp[j]);
                }
            } else {
                const h8f hv = *reinterpret_cast<const h8f*>(
                    (const _Float16*)srcAv + (size_t)row * 32 + ch0 * 8);
#pragma unroll
                for (int j = 0; j < 8; ++j) {
                    const float y = fmaf(sc8[j], (float)hv[j], bi8[j]);
                    v[j] = (short)f2bf(y > 0.f ? y : 0.f);
                }
            }
        }
        const int addr = (r / RPL) * 64 + ((((r % RPL) * NCH + ch0) ^ ((r / RPL) & 7)) * 8);
        *reinterpret_cast<short8*>(&win[addr]) = v;
    }
    __syncthreads();

    const short8* wf8 = reinterpret_cast<const short8*>(wfrag);

    for (int tap = blockIdx.y * 4 + wid; tap < KTAPS; tap += 8) {
        short8 bf[NF];
#pragma unroll
        for (int f = 0; f < NF; ++f) bf[f] = wf8[(tap * NF + f) * 64 + lane];

        const int b  = blockIdx.x * KTAPS + tap;
        const int s0 = (int)starts[b];
        const int s1 = (int)starts[b + 1];

        for (int bb = s0; bb < s1; bb += 32) {
            const bool valid = (bb + col < s1);
            const u32 e  = valid ? entryA[bb + col] : 0u;
            const int r  = (int)(e >> 19) & (WIN - 1);
            const int ro = valid ? (int)(e & 0x7FFFFu) : 0x7FFFF;

            short8 af[NF];
#pragma unroll
            for (int f = 0; f < NF; ++f) {
                const int ch   = f * 2 + half;
                const int addr = (r / RPL) * 64 +
                                 ((((r % RPL) * NCH + ch) ^ ((r / RPL) & 7)) * 8);
                af[f] = *reinterpret_cast<const short8*>(&win[addr]);
            }

            f32x16 cacc;
#pragma unroll
            for (int rr = 0; rr < 16; ++rr) cacc[rr] = 0.f;
#pragma unroll
            for (int f = 0; f < NF; ++f)
                cacc = __builtin_amdgcn_mfma_f32_32x32x16_bf16(af[f], bf[f], cacc, 0, 0, 0);

            const bool oddl = lane & 1;
#pragma unroll
            for (int rr = 0; rr < 16; rr += 2) {
                const int pr0  = (rr & 3) + 8 * (rr >> 2) + 4 * half;
                const int pr1  = ((rr + 1) & 3) + 8 * ((rr + 1) >> 2) + 4 * half;
                const int row0 = __shfl(ro, pr0);
                const int row1 = __shfl(ro, pr1);
                const float a  = cacc[rr], bb2 = cacc[rr + 1];
                const float a2 = __shfl_xor(a, 1);
                const float b2 = __shfl_xor(bb2, 1);
                const float lo = oddl ? b2  : a;
                const float hi = oddl ? bb2 : a2;
                const int  row = oddl ? row1 : row0;
                if (row != 0x7FFFF) {
                    const u32 pk = __builtin_bit_cast(u32,
                        __builtin_amdgcn_cvt_pkrtz(lo, hi));
                    void* ap = (char*)accH + ((size_t)row << 6) + ((u32)(col >> 1) << 2);
                    asm volatile("global_atomic_pk_add_f16 %0, %1, off"
                                 :: "v"(ap), "v"(pk) : "memory");
                }
            }
        }
    }
}

// ---------------------------------------------------------------------------
// BN stats over fp16 acc (HW fp32 atomics into stats[64]) + fused zeroing of
// the NEXT stage's accumulator (zdst may be null).
// ---------------------------------------------------------------------------
__global__ __launch_bounds__(256) void stats_kernel(
    const _Float16* __restrict__ accH, float* __restrict__ stats,
    float4* __restrict__ zdst)
{
    const int tile = blockIdx.x;
    const int tid  = threadIdx.x;
    const int grp  = tid >> 3;
    const int j    = tid & 7;

    if (zdst) {
        const float4 z = {0.f, 0.f, 0.f, 0.f};
        float4* zp = zdst + (size_t)tile * 512;    // 128 rows * 64B = 8KB
        for (int i = tid; i < 512; i += 256) zp[i] = z;
    }

    float cs[4] = {0.f, 0.f, 0.f, 0.f};
    float cq[4] = {0.f, 0.f, 0.f, 0.f};
    for (int rr = grp; rr < 128; rr += 32) {
        const h4 v = *reinterpret_cast<const h4*>(
            &accH[(size_t)(tile * 128 + rr) * 32 + j * 4]);
#pragma unroll
        for (int jj = 0; jj < 4; ++jj) {
            const float f = (float)v[jj];
            cs[jj] += f;
            cq[jj] = fmaf(f, f, cq[jj]);
        }
    }
    __shared__ float ls[32][33], lq[32][33];
#pragma unroll
    for (int jj = 0; jj < 4; ++jj) {
        ls[grp][j * 4 + jj] = cs[jj];
        lq[grp][j * 4 + jj] = cq[jj];
    }
    __syncthreads();
    if (tid < 32) {
        float ts = 0.f, tq = 0.f;
#pragma unroll
        for (int gg = 0; gg < 32; ++gg) { ts += ls[gg][tid]; tq += lq[gg][tid]; }
        unsafeAtomicAdd(&stats[tid], ts);
        unsafeAtomicAdd(&stats[32 + tid], tq);
    }
}

// ---------------------------------------------------------------------------
// Final BN+ReLU -> f32 output.
// ---------------------------------------------------------------------------
__global__ __launch_bounds__(256) void bnout_kernel(
    const _Float16* __restrict__ hsrc,
    const float* __restrict__ stats,
    const float* __restrict__ g,
    const float* __restrict__ bt,
    float* __restrict__ dst, int n)
{
    const int i = blockIdx.x * 256 + threadIdx.x;
    if (i >= n * 8) return;
    const h4 v = *reinterpret_cast<const h4*>(&hsrc[(size_t)i * 4]);
    const int c0 = (i & 7) * 4;
    const float invn = 1.f / (float)n;
    float o[4];
#pragma unroll
    for (int j = 0; j < 4; ++j) {
        const int c   = c0 + j;
        const float m   = stats[c] * invn;
        const float var = fmaxf(stats[32 + c] * invn - m * m, 0.f);
        const float s_  = rsqrtf(var + EPS_BN) * g[c];
        float y = ((float)v[j] - m) * s_ + bt[c];
        o[j] = y > 0.f ? y : 0.f;
    }
    float4 w = {o[0], o[1], o[2], o[3]};
    reinterpret_cast<float4*>(dst)[i] = w;
}

// ---------------------------------------------------------------------------
extern "C" void kernel_launch(void* const* d_in, const int* in_sizes, int n_in,
                              void* d_out, int out_size, void* d_ws, size_t ws_size,
                              hipStream_t stream)
{
    const float* x      = (const float*)d_in[0];
    const float* x_skip = (const float*)d_in[1];
    const float* w_up   = (const float*)d_in[2];
    // d_in[3] = b_up cancels exactly through train-mode BN -> unused.
    const float* g_up   = (const float*)d_in[4];
    const float* bt_up  = (const float*)d_in[5];
    const float* w1     = (const float*)d_in[6];
    const float* g1     = (const float*)d_in[7];
    const float* bt1    = (const float*)d_in[8];
    const float* w2     = (const float*)d_in[9];
    const float* g2     = (const float*)d_in[10];
    const float* bt2    = (const float*)d_in[11];
    const int* up_in    = (const int*)d_in[12];
    const int* up_out   = (const int*)d_in[13];
    const int* c1_in    = (const int*)d_in[14];
    const int* c1_out   = (const int*)d_in[15];
    const int* c2_in    = (const int*)d_in[16];
    const int* c2_out   = (const int*)d_in[17];

    // ---- workspace carve ----
    char* p = (char*)d_ws;
    auto alloc = [&](size_t bytes) { char* r = p; p += (bytes + 255) & ~(size_t)255; return r; };
    _Float16* accA   = (_Float16*) alloc((size_t)N_OUT_C * 32 * 2);   // 25.6 MB
    _Float16* accB   = (_Float16*) alloc((size_t)N_OUT_C * 32 * 2);   // 25.6 MB
    ushort*   wfU    = (ushort*)   alloc(27 * 4 * 64 * 8 * 2);
    ushort*   wf1    = (ushort*)   alloc(27 * 4 * 64 * 8 * 2);
    ushort*   wf2    = (ushort*)   alloc(27 * 2 * 64 * 8 * 2);
    float*    stats  = (float*)    alloc(192 * 4);
    u32*      bsum   = (u32*)      alloc(1024 * 4);
    u32*      htab   = (u32*)      alloc((size_t)HSZ * 4);            // 7.6 MB
    u32*      pbase  = (u32*)      alloc((size_t)HSZ * 4);            // 7.6 MB
    u32*      cnt    = (u32*)      alloc((size_t)NBT * 4);
    u32*      starts = (u32*)      alloc((size_t)(NBT + 1) * 4);
    u32*      entryA = (u32*)      alloc((size_t)ENTT * 4);           // 36.7 MB

    float* out = (float*)d_out;
    const dim3 blk(256);
    const float invn = 1.f / (float)N_OUT_C;
    const int nblkS = (NBT + SCHUNK - 1) / SCHUNK;              // 62
    const dim3 gChunk(NCHK, KTAPS, 3);                          // 15x27x3
    const dim3 gWinKS((NWIN + 255) / 256, KTAPS, 3);            // 7x27x3
    const int bn_blocks = (N_OUT_C * 8 + 255) / 256;
    const size_t accBytes = (size_t)N_OUT_C * 32 * 2;

    // ---- prep: weights + atomic-free sort (no sentinel padding) ----
    wpack_kernel<<<(17280 + 255) / 256, blk, 0, stream>>>(w_up, w1, w2, wfU, wf1, wf2);
    hipMemsetAsync(stats, 0, 192 * sizeof(float), stream);
    hipMemsetAsync(htab, 0, (size_t)HSZ * 4, stream);
    histx_kernel<<<gChunk, blk, 0, stream>>>(up_in, c1_in, c2_in, htab);
    totals_kernel<<<gWinKS, blk, 0, stream>>>(htab, cnt);
    scan_part_kernel<<<nblkS, blk, 0, stream>>>(cnt, bsum, NBT);
    scan_bsum_kernel<<<1, 1024, 0, stream>>>(bsum, nblkS);
    scan_emit_kernel<<<nblkS, blk, 0, stream>>>(cnt, bsum, starts, NBT);
    pbase_kernel<<<gWinKS, blk, 0, stream>>>(htab, starts, pbase);
    fill_kernel<<<gChunk, blk, 0, stream>>>(up_in, up_out, c1_in, c1_out,
                                            c2_in, c2_out, pbase, entryA);

    // ---- stage 1: up conv (x fp32 64ch) -> accA ----
    hipMemsetAsync(accA, 0, accBytes, stream);
    conv_kernel<4, 0><<<dim3(NWIN_U, 2), blk, 0, stream>>>(
        x, nullptr, wfU, entryA, starts, stats, g_up, bt_up, invn, accA, N_IN_C);
    stats_kernel<<<NTILES, blk, 0, stream>>>(accA, stats, (float4*)accB);

    // ---- stage 2: conv1 (bn(accA) | x_skip f32) -> accB ----
    conv_kernel<4, 1><<<dim3(NWIN, 2), blk, 0, stream>>>(
        accA, x_skip, wf1, entryA, starts + NBA, stats, g_up, bt_up, invn, accB, N_OUT_C);
    stats_kernel<<<NTILES, blk, 0, stream>>>(accB, stats + 64, (float4*)accA);

    // ---- stage 3: conv2 (bn(accB)) -> accA ----
    conv_kernel<2, 2><<<dim3(NWIN, 2), blk, 0, stream>>>(
        accB, nullptr, wf2, entryA, starts + 2 * NBA, stats + 64, g1, bt1, invn, accA, N_OUT_C);
    stats_kernel<<<NTILES, blk, 0, stream>>>(accA, stats + 128, nullptr);

    // ---- final BN+ReLU -> d_out (f32) ----
    bnout_kernel<<<bn_blocks, blk, 0, stream>>>(accA, stats + 128, g2, bt2, out, N_OUT_C);
}

// Round 16
// 909.152 us; speedup vs baseline: 1.0515x; 1.0040x over previous
//
#include <hip/hip_runtime.h>

#define EPS_BN 1e-5f

typedef unsigned int u32;
typedef short short8 __attribute__((ext_vector_type(8)));
typedef float f32x16 __attribute__((ext_vector_type(16)));
typedef _Float16 h4 __attribute__((ext_vector_type(4)));
typedef _Float16 h8f __attribute__((ext_vector_type(8)));

constexpr int N_IN_C  = 100000;
constexpr int N_OUT_C = 400000;
constexpr int KTAPS   = 27;
constexpr int M_UP_C  = 100000;
constexpr int M_C_C   = 120000;

constexpr int WIN     = 256;                    // input window rows
constexpr int SH      = 8;                      // log2(WIN)
constexpr int NWIN    = (N_OUT_C + WIN - 1) / WIN;   // 1563
constexpr int NWIN_U  = (N_IN_C  + WIN - 1) / WIN;   // 391
constexpr int NBA     = NWIN * KTAPS;           // 42201 buckets per stage
constexpr int NBT     = 3 * NBA;                // 126603
constexpr int SCHUNK  = 2048;
constexpr int FCH     = 8192;                   // pairs per fill/hist chunk
constexpr int NCHK    = 15;                     // max chunks per (tap,stage)
constexpr int MAXW    = 1600;                   // >= NWIN
constexpr int WSLOTS  = 7;                      // 7*256 >= NWIN
constexpr int NTILES  = N_OUT_C / 128;          // 3125
constexpr int HSZ     = 3 * KTAPS * NCHK * NWIN;
constexpr int ENTT    = 27 * (M_UP_C + 2 * M_C_C);   // exact 9.18M entries

__device__ inline unsigned short f2bf(float f) {
    u32 u = __builtin_bit_cast(u32, f);
    return (unsigned short)((u + 0x7FFFu + ((u >> 16) & 1u)) >> 16);
}

// ---------------------------------------------------------------------------
// Pack weights into MFMA B-fragment layout, bf16.
// ---------------------------------------------------------------------------
__global__ __launch_bounds__(256) void wpack_kernel(
    const float* __restrict__ wU, const float* __restrict__ w1,
    const float* __restrict__ w2,
    ushort* __restrict__ fU, ushort* __restrict__ f1, ushort* __restrict__ f2)
{
    const int t = blockIdx.x * 256 + threadIdx.x;
    const float* w; ushort* dst; int CIN, NF, local;
    if      (t <  6912) { w = wU; dst = fU; CIN = 64; NF = 4; local = t; }
    else if (t < 13824) { w = w1; dst = f1; CIN = 64; NF = 4; local = t - 6912; }
    else if (t < 17280) { w = w2; dst = f2; CIN = 32; NF = 2; local = t - 13824; }
    else return;
    const int lane = local & 63;
    const int fi   = (local >> 6) % NF;
    const int tap  = local / (64 * NF);
    const int half = lane >> 5, colc = lane & 31;
    ushort* o = dst + ((size_t)(tap * NF + fi) * 64 + lane) * 8;
#pragma unroll
    for (int j = 0; j < 8; ++j) {
        const int k = 16 * fi + 8 * half + j;
        o[j] = f2bf(w[((size_t)tap * CIN + k) * 32 + colc]);
    }
}

// ---------------------------------------------------------------------------
// Atomic-free histogram: per (chunk,tap,stage) block, LDS hist -> contiguous
// write of h[s][k][chunk][0..nwin).
// ---------------------------------------------------------------------------
__global__ __launch_bounds__(256) void histx_kernel(
    const int* __restrict__ i0, const int* __restrict__ i1,
    const int* __restrict__ i2, u32* __restrict__ h)
{
    const int s = blockIdx.z, k = blockIdx.y, c = blockIdx.x;
    const int M    = (s == 0) ? M_UP_C : M_C_C;
    const int nwin = (s == 0) ? NWIN_U : NWIN;
    const int m0 = c * FCH;
    if (m0 >= M) return;
    const int cnt = min(FCH, M - m0);
    const int* idx = (s == 0) ? i0 : (s == 1) ? i1 : i2;

    __shared__ u32 lh[NWIN];
    for (int w = threadIdx.x; w < nwin; w += 256) lh[w] = 0;
    __syncthreads();
    const int* ink = idx + (size_t)k * M + m0;
    for (int i = threadIdx.x; i < cnt; i += 256)
        atomicAdd(&lh[ink[i] >> SH], 1u);
    __syncthreads();
    u32* hp = h + ((size_t)(s * KTAPS + k) * NCHK + c) * NWIN;
    for (int w = threadIdx.x; w < nwin; w += 256) hp[w] = lh[w];
}

// ---------------------------------------------------------------------------
// Per-bucket totals.
// ---------------------------------------------------------------------------
__global__ __launch_bounds__(256) void totals_kernel(
    const u32* __restrict__ h, u32* __restrict__ cnt)
{
    const int s = blockIdx.z, k = blockIdx.y;
    const int w = blockIdx.x * 256 + threadIdx.x;
    if (w >= NWIN) return;
    const u32* hp = h + (size_t)(s * KTAPS + k) * NCHK * NWIN + w;
    u32 t = 0;
#pragma unroll
    for (int c = 0; c < NCHK; ++c) t += hp[(size_t)c * NWIN];
    cnt[(size_t)s * NBA + w * KTAPS + k] = t;
}

// ---------------------------------------------------------------------------
// Hierarchical exclusive scan over NBT buckets (EXACT, no padding).
// ---------------------------------------------------------------------------
__global__ __launch_bounds__(256) void scan_part_kernel(
    const u32* __restrict__ cnt, u32* __restrict__ bsum, int nb)
{
    const int i0 = blockIdx.x * SCHUNK + threadIdx.x * 8;
    u32 s = 0;
#pragma unroll
    for (int j = 0; j < 8; ++j) {
        const int i = i0 + j;
        if (i < nb) s += cnt[i];
    }
    __shared__ u32 ls[256];
    ls[threadIdx.x] = s;
    __syncthreads();
    for (int off = 128; off > 0; off >>= 1) {
        if (threadIdx.x < off) ls[threadIdx.x] += ls[threadIdx.x + off];
        __syncthreads();
    }
    if (threadIdx.x == 0) bsum[blockIdx.x] = ls[0];
}

__global__ __launch_bounds__(1024) void scan_bsum_kernel(
    u32* __restrict__ bsum, int nblk)
{
    __shared__ u32 tmp[1024];
    const int t = threadIdx.x;
    const u32 v = (t < nblk) ? bsum[t] : 0u;
    tmp[t] = v;
    __syncthreads();
    for (int off = 1; off < 1024; off <<= 1) {
        const u32 u = (t >= off) ? tmp[t - off] : 0u;
        __syncthreads();
        tmp[t] += u;
        __syncthreads();
    }
    if (t < nblk) bsum[t] = tmp[t] - v;
}

__global__ __launch_bounds__(256) void scan_emit_kernel(
    const u32* __restrict__ cnt, const u32* __restrict__ bsum,
    u32* __restrict__ starts, int nb)
{
    const int t  = threadIdx.x;
    const int i0 = blockIdx.x * SCHUNK + t * 8;
    u32 vals[8];
    u32 s = 0;
#pragma unroll
    for (int j = 0; j < 8; ++j) {
        const int i = i0 + j;
        const u32 c = (i < nb) ? cnt[i] : 0u;
        vals[j] = c;
        s += c;
    }
    __shared__ u32 ls[256];
    ls[t] = s;
    __syncthreads();
    for (int off = 1; off < 256; off <<= 1) {
        const u32 u = (t >= off) ? ls[t - off] : 0u;
        __syncthreads();
        ls[t] += u;
        __syncthreads();
    }
    u32 run = bsum[blockIdx.x] + ls[t] - s;
#pragma unroll
    for (int j = 0; j < 8; ++j) {
        const int i = i0 + j;
        if (i < nb) starts[i] = run;
        run += vals[j];
    }
    if (blockIdx.x == gridDim.x - 1 && t == 255) starts[nb] = run;
}

// ---------------------------------------------------------------------------
// Per-(bucket,chunk) bases.
// ---------------------------------------------------------------------------
__global__ __launch_bounds__(256) void pbase_kernel(
    const u32* __restrict__ h, const u32* __restrict__ starts,
    u32* __restrict__ pb)
{
    const int s = blockIdx.z, k = blockIdx.y;
    const int w = blockIdx.x * 256 + threadIdx.x;
    if (w >= NWIN) return;
    u32 run = starts[(size_t)s * NBA + w * KTAPS + k];
    const size_t base = (size_t)(s * KTAPS + k) * NCHK * NWIN + w;
#pragma unroll
    for (int c = 0; c < NCHK; ++c) {
        pb[base + (size_t)c * NWIN] = run;
        run += h[base + (size_t)c * NWIN];
    }
}

// ---------------------------------------------------------------------------
// Atomic-free binned fill (deterministic bases from pbase).
// Entry = (in & (WIN-1)) << 19 | out_row.
// ---------------------------------------------------------------------------
__global__ __launch_bounds__(256) void fill_kernel(
    const int* __restrict__ in0, const int* __restrict__ out0,
    const int* __restrict__ in1, const int* __restrict__ out1,
    const int* __restrict__ in2, const int* __restrict__ out2,
    const u32* __restrict__ pb, u32* __restrict__ entryA)
{
    __shared__ u32 hist[MAXW];
    __shared__ u32 lofs[MAXW];
    __shared__ u32 gbase[MAXW];
    __shared__ u32 lent[FCH];
    __shared__ u32 psum[256];

    const int s = blockIdx.z;
    const int* in_idx  = (s == 0) ? in0  : (s == 1) ? in1  : in2;
    const int* out_idx = (s == 0) ? out0 : (s == 1) ? out1 : out2;
    const int  M       = (s == 0) ? M_UP_C : M_C_C;
    const int  nwin    = (s == 0) ? NWIN_U : NWIN;

    const int k   = blockIdx.y;
    const int m0  = blockIdx.x * FCH;
    if (m0 >= M) return;
    const int cnt = min(FCH, M - m0);
    const int t   = threadIdx.x;

    const u32* pbk = pb + ((size_t)(s * KTAPS + k) * NCHK + blockIdx.x) * NWIN;

    for (int w = t; w < nwin; w += 256) {
        hist[w]  = 0;
        gbase[w] = pbk[w];
    }
    __syncthreads();

    const int* ink  = in_idx  + (size_t)k * M + m0;
    const int* outk = out_idx + (size_t)k * M + m0;

    for (int i = t; i < cnt; i += 256)
        atomicAdd(&hist[ink[i] >> SH], 1u);
    __syncthreads();

    u32 loc[WSLOTS];
    u32 ssum = 0;
#pragma unroll
    for (int j = 0; j < WSLOTS; ++j) {
        const int w = t * WSLOTS + j;
        const u32 c = (w < nwin) ? hist[w] : 0u;
        loc[j] = ssum;
        ssum += c;
    }
    psum[t] = ssum;
    __syncthreads();
    for (int off = 1; off < 256; off <<= 1) {
        const u32 v = (t >= off) ? psum[t - off] : 0u;
        __syncthreads();
        psum[t] += v;
        __syncthreads();
    }
    const u32 tbase = psum[t] - ssum;
#pragma unroll
    for (int j = 0; j < WSLOTS; ++j) {
        const int w = t * WSLOTS + j;
        if (w < nwin) lofs[w] = tbase + loc[j];
    }
    __syncthreads();

    for (int i = t; i < cnt; i += 256) {
        const int in = ink[i];
        const int o  = outk[i];
        const int w  = in >> SH;
        const u32 pp = atomicAdd(&lofs[w], 1u);
        lent[pp] = ((u32)(in & (WIN - 1)) << 19) | (u32)o;
    }
    __syncthreads();

    for (int w = t; w < nwin; w += 256) {
        const u32 c = hist[w];
        if (!c) continue;
        const u32 lo = lofs[w] - c;
        const u32 gb = gbase[w];
        for (u32 j = 0; j < c; ++j)
            entryA[gb + j] = lent[lo + j];
    }
}

// ---------------------------------------------------------------------------
// Conv with fused BN+ReLU staging; tail-masked batches; tap stride is
// parametric in gridDim.y (finer tap-split -> more resident blocks).
// MODE 0: src = x fp32 64ch raw.  MODE 1: srcA = prev fp16 acc (BN),
// srcB = x_skip fp32 raw.  MODE 2: src = prev fp16 acc (BN).
// Scatter via packed fp16 HW atomics.
// ---------------------------------------------------------------------------
template <int NF, int MODE>
__global__ __launch_bounds__(256) void conv_kernel(
    const void* __restrict__ srcAv, const void* __restrict__ srcBv,
    const ushort* __restrict__ wfrag,
    const u32* __restrict__ entryA, const u32* __restrict__ starts,
    const float* __restrict__ st, const float* __restrict__ g,
    const float* __restrict__ bt, float invn,
    _Float16* __restrict__ accH, int n_src)
{
    constexpr int NCH = NF * 2;
    constexpr int RPL = 8 / NCH;
    __shared__ ushort win[WIN * NF * 16];   // 32KB (NF=4) / 16KB (NF=2)

    const int w0   = blockIdx.x * WIN;
    const int tid  = threadIdx.x;
    const int lane = tid & 63;
    const int wid  = tid >> 6;
    const int col  = lane & 31;
    const int half = lane >> 5;
    const int ch0  = tid % NCH;             // loop-invariant staging channel

    float sc8[8], bi8[8];
    const bool needbn = (MODE == 2) || (MODE == 1 && ch0 < 4);
    if (MODE != 0 && needbn) {
#pragma unroll
        for (int j = 0; j < 8; ++j) {
            const int c = ch0 * 8 + j;
            const float m   = st[c] * invn;
            const float var = fmaxf(st[32 + c] * invn - m * m, 0.f);
            const float s_  = rsqrtf(var + EPS_BN) * g[c];
            sc8[j] = s_;
            bi8[j] = fmaf(-m, s_, bt[c]);
        }
    }

    for (int i = tid; i < WIN * NCH; i += 256) {
        const int r  = i / NCH;
        const int row = w0 + r;
        short8 v = {0, 0, 0, 0, 0, 0, 0, 0};
        if (row < n_src) {
            if (MODE == 0) {
                const float* sp = (const float*)srcAv + (size_t)row * 64 + ch0 * 8;
#pragma unroll
                for (int j = 0; j < 8; ++j) v[j] = (short)f2bf(sp[j]);
            } else if (MODE == 1) {
                if (ch0 < 4) {
                    const h8f hv = *reinterpret_cast<const h8f*>(
                        (const _Float16*)srcAv + (size_t)row * 32 + ch0 * 8);
#pragma unroll
                    for (int j = 0; j < 8; ++j) {
                        const float y = fmaf(sc8[j], (float)hv[j], bi8[j]);
                        v[j] = (short)f2bf(y > 0.f ? y : 0.f);
                    }
                } else {
                    const float* sp = (const float*)srcBv + (size_t)row * 32 + (ch0 - 4) * 8;
#pragma unroll
                    for (int j = 0; j < 8; ++j) v[j] = (short)f2bf(sp[j]);
                }
            } else {
                const h8f hv = *reinterpret_cast<const h8f*>(
                    (const _Float16*)srcAv + (size_t)row * 32 + ch0 * 8);
#pragma unroll
                for (int j = 0; j < 8; ++j) {
                    const float y = fmaf(sc8[j], (float)hv[j], bi8[j]);
                    v[j] = (short)f2bf(y > 0.f ? y : 0.f);
                }
            }
        }
        const int addr = (r / RPL) * 64 + ((((r % RPL) * NCH + ch0) ^ ((r / RPL) & 7)) * 8);
        *reinterpret_cast<short8*>(&win[addr]) = v;
    }
    __syncthreads();

    const short8* wf8 = reinterpret_cast<const short8*>(wfrag);
    const int tstride = gridDim.y << 2;     // taps advance by 4*gridDim.y

    for (int tap = blockIdx.y * 4 + wid; tap < KTAPS; tap += tstride) {
        short8 bf[NF];
#pragma unroll
        for (int f = 0; f < NF; ++f) bf[f] = wf8[(tap * NF + f) * 64 + lane];

        const int b  = blockIdx.x * KTAPS + tap;
        const int s0 = (int)starts[b];
        const int s1 = (int)starts[b + 1];

        for (int bb = s0; bb < s1; bb += 32) {
            const bool valid = (bb + col < s1);
            const u32 e  = valid ? entryA[bb + col] : 0u;
            const int r  = (int)(e >> 19) & (WIN - 1);
            const int ro = valid ? (int)(e & 0x7FFFFu) : 0x7FFFF;

            short8 af[NF];
#pragma unroll
            for (int f = 0; f < NF; ++f) {
                const int ch   = f * 2 + half;
                const int addr = (r / RPL) * 64 +
                                 ((((r % RPL) * NCH + ch) ^ ((r / RPL) & 7)) * 8);
                af[f] = *reinterpret_cast<const short8*>(&win[addr]);
            }

            f32x16 cacc;
#pragma unroll
            for (int rr = 0; rr < 16; ++rr) cacc[rr] = 0.f;
#pragma unroll
            for (int f = 0; f < NF; ++f)
                cacc = __builtin_amdgcn_mfma_f32_32x32x16_bf16(af[f], bf[f], cacc, 0, 0, 0);

            const bool oddl = lane & 1;
#pragma unroll
            for (int rr = 0; rr < 16; rr += 2) {
                const int pr0  = (rr & 3) + 8 * (rr >> 2) + 4 * half;
                const int pr1  = ((rr + 1) & 3) + 8 * ((rr + 1) >> 2) + 4 * half;
                const int row0 = __shfl(ro, pr0);
                const int row1 = __shfl(ro, pr1);
                const float a  = cacc[rr], bb2 = cacc[rr + 1];
                const float a2 = __shfl_xor(a, 1);
                const float b2 = __shfl_xor(bb2, 1);
                const float lo = oddl ? b2  : a;
                const float hi = oddl ? bb2 : a2;
                const int  row = oddl ? row1 : row0;
                if (row != 0x7FFFF) {
                    const u32 pk = __builtin_bit_cast(u32,
                        __builtin_amdgcn_cvt_pkrtz(lo, hi));
                    void* ap = (char*)accH + ((size_t)row << 6) + ((u32)(col >> 1) << 2);
                    asm volatile("global_atomic_pk_add_f16 %0, %1, off"
                                 :: "v"(ap), "v"(pk) : "memory");
                }
            }
        }
    }
}

// ---------------------------------------------------------------------------
// BN stats over fp16 acc (HW fp32 atomics into stats[64]) + fused zeroing of
// the NEXT stage's accumulator (zdst may be null).
// ---------------------------------------------------------------------------
__global__ __launch_bounds__(256) void stats_kernel(
    const _Float16* __restrict__ accH, float* __restrict__ stats,
    float4* __restrict__ zdst)
{
    const int tile = blockIdx.x;
    const int tid  = threadIdx.x;
    const int grp  = tid >> 3;
    const int j    = tid & 7;

    if (zdst) {
        const float4 z = {0.f, 0.f, 0.f, 0.f};
        float4* zp = zdst + (size_t)tile * 512;    // 128 rows * 64B = 8KB
        for (int i = tid; i < 512; i += 256) zp[i] = z;
    }

    float cs[4] = {0.f, 0.f, 0.f, 0.f};
    float cq[4] = {0.f, 0.f, 0.f, 0.f};
    for (int rr = grp; rr < 128; rr += 32) {
        const h4 v = *reinterpret_cast<const h4*>(
            &accH[(size_t)(tile * 128 + rr) * 32 + j * 4]);
#pragma unroll
        for (int jj = 0; jj < 4; ++jj) {
            const float f = (float)v[jj];
            cs[jj] += f;
            cq[jj] = fmaf(f, f, cq[jj]);
        }
    }
    __shared__ float ls[32][33], lq[32][33];
#pragma unroll
    for (int jj = 0; jj < 4; ++jj) {
        ls[grp][j * 4 + jj] = cs[jj];
        lq[grp][j * 4 + jj] = cq[jj];
    }
    __syncthreads();
    if (tid < 32) {
        float ts = 0.f, tq = 0.f;
#pragma unroll
        for (int gg = 0; gg < 32; ++gg) { ts += ls[gg][tid]; tq += lq[gg][tid]; }
        unsafeAtomicAdd(&stats[tid], ts);
        unsafeAtomicAdd(&stats[32 + tid], tq);
    }
}

// ---------------------------------------------------------------------------
// Final BN+ReLU -> f32 output.
// ---------------------------------------------------------------------------
__global__ __launch_bounds__(256) void bnout_kernel(
    const _Float16* __restrict__ hsrc,
    const float* __restrict__ stats,
    const float* __restrict__ g,
    const float* __restrict__ bt,
    float* __restrict__ dst, int n)
{
    const int i = blockIdx.x * 256 + threadIdx.x;
    if (i >= n * 8) return;
    const h4 v = *reinterpret_cast<const h4*>(&hsrc[(size_t)i * 4]);
    const int c0 = (i & 7) * 4;
    const float invn = 1.f / (float)n;
    float o[4];
#pragma unroll
    for (int j = 0; j < 4; ++j) {
        const int c   = c0 + j;
        const float m   = stats[c] * invn;
        const float var = fmaxf(stats[32 + c] * invn - m * m, 0.f);
        const float s_  = rsqrtf(var + EPS_BN) * g[c];
        float y = ((float)v[j] - m) * s_ + bt[c];
        o[j] = y > 0.f ? y : 0.f;
    }
    float4 w = {o[0], o[1], o[2], o[3]};
    reinterpret_cast<float4*>(dst)[i] = w;
}

// ---------------------------------------------------------------------------
extern "C" void kernel_launch(void* const* d_in, const int* in_sizes, int n_in,
                              void* d_out, int out_size, void* d_ws, size_t ws_size,
                              hipStream_t stream)
{
    const float* x      = (const float*)d_in[0];
    const float* x_skip = (const float*)d_in[1];
    const float* w_up   = (const float*)d_in[2];
    // d_in[3] = b_up cancels exactly through train-mode BN -> unused.
    const float* g_up   = (const float*)d_in[4];
    const float* bt_up  = (const float*)d_in[5];
    const float* w1     = (const float*)d_in[6];
    const float* g1     = (const float*)d_in[7];
    const float* bt1    = (const float*)d_in[8];
    const float* w2     = (const float*)d_in[9];
    const float* g2     = (const float*)d_in[10];
    const float* bt2    = (const float*)d_in[11];
    const int* up_in    = (const int*)d_in[12];
    const int* up_out   = (const int*)d_in[13];
    const int* c1_in    = (const int*)d_in[14];
    const int* c1_out   = (const int*)d_in[15];
    const int* c2_in    = (const int*)d_in[16];
    const int* c2_out   = (const int*)d_in[17];

    // ---- workspace carve ----
    char* p = (char*)d_ws;
    auto alloc = [&](size_t bytes) { char* r = p; p += (bytes + 255) & ~(size_t)255; return r; };
    _Float16* accA   = (_Float16*) alloc((size_t)N_OUT_C * 32 * 2);   // 25.6 MB
    _Float16* accB   = (_Float16*) alloc((size_t)N_OUT_C * 32 * 2);   // 25.6 MB
    ushort*   wfU    = (ushort*)   alloc(27 * 4 * 64 * 8 * 2);
    ushort*   wf1    = (ushort*)   alloc(27 * 4 * 64 * 8 * 2);
    ushort*   wf2    = (ushort*)   alloc(27 * 2 * 64 * 8 * 2);
    float*    stats  = (float*)    alloc(192 * 4);
    u32*      bsum   = (u32*)      alloc(1024 * 4);
    u32*      htab   = (u32*)      alloc((size_t)HSZ * 4);            // 7.6 MB
    u32*      pbase  = (u32*)      alloc((size_t)HSZ * 4);            // 7.6 MB
    u32*      cnt    = (u32*)      alloc((size_t)NBT * 4);
    u32*      starts = (u32*)      alloc((size_t)(NBT + 1) * 4);
    u32*      entryA = (u32*)      alloc((size_t)ENTT * 4);           // 36.7 MB

    float* out = (float*)d_out;
    const dim3 blk(256);
    const float invn = 1.f / (float)N_OUT_C;
    const int nblkS = (NBT + SCHUNK - 1) / SCHUNK;              // 62
    const dim3 gChunk(NCHK, KTAPS, 3);                          // 15x27x3
    const dim3 gWinKS((NWIN + 255) / 256, KTAPS, 3);            // 7x27x3
    const int bn_blocks = (N_OUT_C * 8 + 255) / 256;
    const size_t accBytes = (size_t)N_OUT_C * 32 * 2;

    // ---- prep: weights + atomic-free sort ----
    wpack_kernel<<<(17280 + 255) / 256, blk, 0, stream>>>(w_up, w1, w2, wfU, wf1, wf2);
    hipMemsetAsync(stats, 0, 192 * sizeof(float), stream);
    hipMemsetAsync(htab, 0, (size_t)HSZ * 4, stream);
    histx_kernel<<<gChunk, blk, 0, stream>>>(up_in, c1_in, c2_in, htab);
    totals_kernel<<<gWinKS, blk, 0, stream>>>(htab, cnt);
    scan_part_kernel<<<nblkS, blk, 0, stream>>>(cnt, bsum, NBT);
    scan_bsum_kernel<<<1, 1024, 0, stream>>>(bsum, nblkS);
    scan_emit_kernel<<<nblkS, blk, 0, stream>>>(cnt, bsum, starts, NBT);
    pbase_kernel<<<gWinKS, blk, 0, stream>>>(htab, starts, pbase);
    fill_kernel<<<gChunk, blk, 0, stream>>>(up_in, up_out, c1_in, c1_out,
                                            c2_in, c2_out, pbase, entryA);

    // ---- stage 1: up conv (x fp32 64ch) -> accA ----
    hipMemsetAsync(accA, 0, accBytes, stream);
    conv_kernel<4, 0><<<dim3(NWIN_U, 4), blk, 0, stream>>>(
        x, nullptr, wfU, entryA, starts, stats, g_up, bt_up, invn, accA, N_IN_C);
    stats_kernel<<<NTILES, blk, 0, stream>>>(accA, stats, (float4*)accB);

    // ---- stage 2: conv1 (bn(accA) | x_skip f32) -> accB ----
    conv_kernel<4, 1><<<dim3(NWIN, 4), blk, 0, stream>>>(
        accA, x_skip, wf1, entryA, starts + NBA, stats, g_up, bt_up, invn, accB, N_OUT_C);
    stats_kernel<<<NTILES, blk, 0, stream>>>(accB, stats + 64, (float4*)accA);

    // ---- stage 3: conv2 (bn(accB)) -> accA ----
    conv_kernel<2, 2><<<dim3(NWIN, 4), blk, 0, stream>>>(
        accB, nullptr, wf2, entryA, starts + 2 * NBA, stats + 64, g1, bt1, invn, accA, N_OUT_C);
    stats_kernel<<<NTILES, blk, 0, stream>>>(accA, stats + 128, nullptr);

    // ---- final BN+ReLU -> d_out (f32) ----
    bnout_kernel<<<bn_blocks, blk, 0, stream>>>(accA, stats + 128, g2, bt2, out, N_OUT_C);
}